// Round 8
// baseline (390.544 us; speedup 1.0000x reference)
//
#include <hip/hip_runtime.h>
#include <hip/hip_bf16.h>
#include <math.h>

#define AS1 __attribute__((address_space(1)))
#define AS3 __attribute__((address_space(3)))

typedef __bf16 bf16x8 __attribute__((ext_vector_type(8)));
typedef __bf16 bf16x4 __attribute__((ext_vector_type(4)));
typedef float  f32x4  __attribute__((ext_vector_type(4)));

static constexpr int   N_ROWS   = 10000;
static constexpr int   D        = 256;           // K for all GEMMs
static constexpr float INV_TAU  = 2.0f;          // 1/0.5

// gram tiling: 128x128 tiles, rows padded to 10112
static constexpr int   T        = 79;            // ceil(10000/128)
static constexpr int   NP       = T * 128;       // 10112
static constexpr float PADF     = 112.0f;        // NP - N_ROWS (exp(0)=1 each)
static constexpr int   SPR     = 10;             // strips per row (ceil(79/8))
static constexpr int   BPJ     = T * SPR;        // 790 strip-blocks per job
static constexpr int   NWGG    = 5 * BPJ;        // 3950

// proj tiling (128x128 structure)
static constexpr int   PT       = 79;

// ---------------------------------------------------------------------------
// 128x128 tile GEMM helper (projection GEMMs only). K=256, BK=64,
// single-buffer, XOR-swizzled LDS via pre-swizzled global_load_lds source.
// ---------------------------------------------------------------------------
__device__ __forceinline__ void tile_gemm_128(
    const __bf16* __restrict__ Abase, const __bf16* __restrict__ Bbase,
    char* ldsA, char* ldsB, int tid, f32x4 acc[4][4])
{
  const int l      = tid & 63;
  const int wr     = (tid >> 7) & 1;
  const int wc     = (tid >> 6) & 1;
  const int srow   = tid >> 3;
  const int schunk = tid & 7;
  const int lrow   = l & 15;
  const int lk     = l >> 4;

  for (int kt = 0; kt < 4; ++kt) {
    __syncthreads();
    const int kbase = kt * 64;
#pragma unroll
    for (int rr = 0; rr < 4; ++rr) {
      const int row = rr * 32 + srow;
      const int lc  = schunk ^ (row & 7);
      const __bf16* ga = Abase + (size_t)row * D + kbase + lc * 8;
      const __bf16* gb = Bbase + (size_t)row * D + kbase + lc * 8;
      __builtin_amdgcn_global_load_lds((const AS1 void*)ga,
          (AS3 void*)(ldsA + rr * 4096 + tid * 16), 16, 0, 0);
      __builtin_amdgcn_global_load_lds((const AS1 void*)gb,
          (AS3 void*)(ldsB + rr * 4096 + tid * 16), 16, 0, 0);
    }
    __syncthreads();
#pragma unroll
    for (int ks = 0; ks < 2; ++ks) {
      bf16x8 af[4], bfr[4];
#pragma unroll
      for (int m = 0; m < 4; ++m) {
        const int row = wr * 64 + m * 16 + lrow;
        const int off = row * 128 + ((ks * 64 + lk * 16) ^ ((row & 7) << 4));
        af[m] = *(const bf16x8*)(ldsA + off);
      }
#pragma unroll
      for (int n = 0; n < 4; ++n) {
        const int row = wc * 64 + n * 16 + lrow;
        const int off = row * 128 + ((ks * 64 + lk * 16) ^ ((row & 7) << 4));
        bfr[n] = *(const bf16x8*)(ldsB + off);
      }
#pragma unroll
      for (int m = 0; m < 4; ++m)
#pragma unroll
        for (int n = 0; n < 4; ++n)
          acc[m][n] = __builtin_amdgcn_mfma_f32_16x16x32_bf16(
              af[m], bfr[n], acc[m][n], 0, 0, 0);
    }
  }
}

// ---------------------------------------------------------------------------
// Gram kernel, strip-mined, A-in-registers: each block owns up to 8 tiles
// (128x128) sharing one A-panel row r. The wave's A fragments for the FULL
// K=256 are loaded from global into 128 VGPRs once per strip (mapping
// identical to what the proven LDS path delivered: lane l, frag m, slab kc
// -> A[(wr*64+m*16+(l&15))*D + kc*32 + (l>>4)*8], 16B aligned). LDS carries
// only B: BK=64 slabs (16 KiB), 3 buffers, depth-2 prefetch, counted
// vmcnt(4) + one s_barrier per K-step (r7's race-safe schedule). LDS bytes
// per MFMA halved vs r7 -> MFMA pipe becomes the pole.
// ---------------------------------------------------------------------------
__global__ __launch_bounds__(256, 2) void gram_kernel(
    const __bf16* __restrict__ p1, const __bf16* __restrict__ p2,
    const __bf16* __restrict__ p3, float* __restrict__ S)
{
  const int bid = blockIdx.x;
  const int job = bid / BPJ;
  const int t0  = bid % BPJ;
  const int r   = t0 / SPR;
  const int s   = t0 % SPR;
  int cstart = s * 8;
  const int cend = min(cstart + 8, T);

  const __bf16 *P, *Q;
  float *Srow, *Scol;
  bool sym = false;
  if (job == 0)      { P = p1; Q = p2; Srow = S + 1 * NP; Scol = S + 3 * NP; }
  else if (job == 1) { P = p1; Q = p3; Srow = S + 2 * NP; Scol = nullptr; }
  else if (job == 2) { P = p2; Q = p3; Srow = S + 5 * NP; Scol = nullptr; }
  else if (job == 3) { P = p1; Q = p1; Srow = S + 0 * NP; Scol = S + 0 * NP;
                       sym = true; cstart = max(cstart, r); }
  else               { P = p2; Q = p2; Srow = S + 4 * NP; Scol = S + 4 * NP;
                       sym = true; cstart = max(cstart, r); }
  const int len = cend - cstart;
  if (len <= 0) return;
  const int nsteps = len * 4;           // BK=64 steps

  // 3 bufs x 16 KiB (B only) = 48 KiB
  __shared__ __align__(16) char lds[49152];

  const int tid  = threadIdx.x;
  const int l    = tid & 63;
  const int wave = tid >> 6;
  const int wr   = wave >> 1;      // 64-row half
  const int wc   = wave & 1;       // 64-col half
  const int lrow = l & 15;
  const int lk   = l >> 4;

  // ---- A fragments for the whole strip in registers (128 VGPR) ----
  const __bf16* Abase = P + (size_t)r * 128 * D;
  bf16x8 afr[8][4];
#pragma unroll
  for (int kc = 0; kc < 8; ++kc)
#pragma unroll
    for (int m = 0; m < 4; ++m)
      afr[kc][m] = *(const bf16x8*)(Abase +
          (size_t)(wr * 64 + m * 16 + lrow) * D + kc * 32 + lk * 8);

  // B-frag LDS read offsets in a 16 KiB [128 rows][8 chunks] slab:
  // off = row*128 + ((chunk ^ (row&7))<<4); ks=1 toggles byte 64.
  int offB0[4];
#pragma unroll
  for (int n = 0; n < 4; ++n) {
    const int row = wc * 64 + n * 16 + lrow;
    offB0[n] = row * 128 + ((lk ^ (row & 7)) << 4);
  }

  // staging: 1024 16B-chunks per slab, 4 per thread, inverse-swizzled source
  int spos[4], soff[4];
#pragma unroll
  for (int j = 0; j < 4; ++j) {
    const int p = tid + j * 256;
    const int row = p >> 3, pc = p & 7;
    spos[j] = p * 16;
    soff[j] = row * D + (pc ^ (row & 7)) * 8;
  }

  auto stage = [&](int bufoff, int i) {
    const int c  = cstart + (i >> 2);
    const int kb = (i & 3) * 64;
    const __bf16* B0 = Q + (size_t)c * 128 * D + kb;
    char* lb = lds + bufoff;
#pragma unroll
    for (int j = 0; j < 4; ++j)
      __builtin_amdgcn_global_load_lds((const AS1 void*)(B0 + soff[j]),
          (AS3 void*)(lb + spos[j]), 16, 0, 0);
  };

  f32x4 rsum[4];
#pragma unroll
  for (int m = 0; m < 4; ++m)
#pragma unroll
    for (int q = 0; q < 4; ++q) rsum[m][q] = 0.f;

  // prologue: two B-slabs in flight
  stage(0, 0);
  stage(16384, 1);

  int rb = 0;                       // LDS byte offset of slab i's buffer
  for (int tt = 0; tt < len; ++tt) {
    f32x4 acc[4][4];
#pragma unroll
    for (int m = 0; m < 4; ++m)
#pragma unroll
      for (int n = 0; n < 4; ++n)
#pragma unroll
        for (int q = 0; q < 4; ++q) acc[m][n][q] = 0.f;

#pragma unroll
    for (int kt = 0; kt < 4; ++kt) {
      const int i = tt * 4 + kt;
      // wait for slab i only (in-order retire; depth-2 prefetch = 4 loads
      // stay outstanding); then make it visible to all waves
      if (i < nsteps - 1) asm volatile("s_waitcnt vmcnt(4)" ::: "memory");
      else                asm volatile("s_waitcnt vmcnt(0)" ::: "memory");
      __builtin_amdgcn_s_barrier();
      __builtin_amdgcn_sched_barrier(0);
      // prefetch slab i+2 into buf (i+2)%3 == (i-1)%3 (readers done: barrier)
      if (i + 2 < nsteps) {
        int sb = rb + 32768; if (sb >= 49152) sb -= 49152;
        stage(sb, i + 2);
      }
      const char* lb = lds + rb;
#pragma unroll
      for (int ks = 0; ks < 2; ++ks) {
        bf16x8 bfr[4];
#pragma unroll
        for (int n = 0; n < 4; ++n)
          bfr[n] = *(const bf16x8*)(lb + (offB0[n] ^ (ks << 6)));
#pragma unroll
        for (int m = 0; m < 4; ++m)
#pragma unroll
          for (int n = 0; n < 4; ++n)
            acc[m][n] = __builtin_amdgcn_mfma_f32_16x16x32_bf16(
                afr[kt * 2 + ks][m], bfr[n], acc[m][n], 0, 0, 0);
      }
      rb += 16384; if (rb == 49152) rb = 0;
    }

    // ---- tile epilogue (runs while prefetched loads are in flight) ----
    const int c = cstart + tt;
#pragma unroll
    for (int m = 0; m < 4; ++m)
#pragma unroll
      for (int n = 0; n < 4; ++n)
#pragma unroll
        for (int q = 0; q < 4; ++q)
          acc[m][n][q] = __expf(acc[m][n][q] * INV_TAU);

#pragma unroll
    for (int m = 0; m < 4; ++m)
      rsum[m] += acc[m][0] + acc[m][1] + acc[m][2] + acc[m][3];

    const bool docol = Scol && (!sym || c > r);
    if (docol) {
#pragma unroll
      for (int n = 0; n < 4; ++n) {
        float sc = 0.f;
#pragma unroll
        for (int m = 0; m < 4; ++m)
#pragma unroll
          for (int q = 0; q < 4; ++q) sc += acc[m][n][q];
        sc += __shfl_xor(sc, 16, 64);
        sc += __shfl_xor(sc, 32, 64);
        if (l < 16) atomicAdd(&Scol[c * 128 + wc * 64 + n * 16 + l], sc);
      }
    }
  }

  // ---- strip epilogue: row sums (one atomic set per strip) ----
#pragma unroll
  for (int m = 0; m < 4; ++m) {
#pragma unroll
    for (int mask = 1; mask < 16; mask <<= 1)
#pragma unroll
      for (int q = 0; q < 4; ++q)
        rsum[m][q] += __shfl_xor(rsum[m][q], mask, 64);
    if ((l & 15) == 0) {
      const int grow = r * 128 + wr * 64 + m * 16 + lk * 4;
#pragma unroll
      for (int q = 0; q < 4; ++q) atomicAdd(&Srow[grow + q], rsum[m][q]);
    }
  }
}

// ---------------------------------------------------------------------------
// Projection GEMM: C = A @ B^T + bias, MODE 0: elu -> bf16, MODE 1: f32.
// ---------------------------------------------------------------------------
template <int MODE>
__global__ __launch_bounds__(256, 2) void proj_kernel(
    const __bf16* __restrict__ A, const __bf16* __restrict__ B,
    const float* __restrict__ bias, void* __restrict__ out)
{
  const int r = blockIdx.x, c = blockIdx.y;
  __shared__ __align__(16) char lds[32768];
  f32x4 acc[4][4];
#pragma unroll
  for (int m = 0; m < 4; ++m)
#pragma unroll
    for (int n = 0; n < 4; ++n)
#pragma unroll
      for (int q = 0; q < 4; ++q) acc[m][n][q] = 0.f;

  tile_gemm_128(A + (size_t)r * 128 * D, B + (size_t)c * 128 * D,
                lds, lds + 16384, threadIdx.x, acc);

  const int tid = threadIdx.x, l = tid & 63;
  const int wr = (tid >> 7) & 1, wc = (tid >> 6) & 1;
#pragma unroll
  for (int n = 0; n < 4; ++n) {
    const int gcol = c * 128 + wc * 64 + n * 16 + (l & 15);
    const float bn = bias[gcol];
#pragma unroll
    for (int m = 0; m < 4; ++m) {
#pragma unroll
      for (int q = 0; q < 4; ++q) {
        const int grow = r * 128 + wr * 64 + m * 16 + (l >> 4) * 4 + q;
        float v = acc[m][n][q] + bn;
        if (MODE == 0) {
          float o = v > 0.f ? v : (__expf(v) - 1.f);   // ELU
          ((__bf16*)out)[(size_t)grow * D + gcol] = (__bf16)o;
        } else {
          ((float*)out)[(size_t)grow * D + gcol] = v;
        }
      }
    }
  }
}

// ---------------------------------------------------------------------------
__global__ void cast_kernel(const float* __restrict__ src,
                            __bf16* __restrict__ dst, int n)
{
  int idx = (blockIdx.x * blockDim.x + threadIdx.x) * 4;
  const int stride = gridDim.x * blockDim.x * 4;
  for (; idx < n; idx += stride) {
    const float4 v = *(const float4*)(src + idx);
    bf16x4 o;
    o[0] = (__bf16)v.x; o[1] = (__bf16)v.y;
    o[2] = (__bf16)v.z; o[3] = (__bf16)v.w;
    *(bf16x4*)(dst + idx) = o;
  }
}

// one wave per row: L2-normalize; padded rows written as exact zeros
__global__ void norm_kernel(const float* __restrict__ praw,
                            __bf16* __restrict__ p)
{
  const int row = blockIdx.x * 4 + (threadIdx.x >> 6);
  const int l = threadIdx.x & 63;
  const size_t base = (size_t)row * D + l * 4;
  if (row < N_ROWS) {
    const float4 v = *(const float4*)(praw + base);
    float ss = v.x * v.x + v.y * v.y + v.z * v.z + v.w * v.w;
#pragma unroll
    for (int mask = 1; mask < 64; mask <<= 1) ss += __shfl_xor(ss, mask, 64);
    const float inv = 1.0f / fmaxf(sqrtf(ss), 1e-12f);
    bf16x4 o;
    o[0] = (__bf16)(v.x * inv); o[1] = (__bf16)(v.y * inv);
    o[2] = (__bf16)(v.z * inv); o[3] = (__bf16)(v.w * inv);
    *(bf16x4*)(p + base) = o;
  } else {
    bf16x4 o;
    o[0] = o[1] = o[2] = o[3] = (__bf16)0.0f;
    *(bf16x4*)(p + base) = o;
  }
}

// per-row diagonal terms: dg [5][NP] = exp(d11,d22,d12,d13,d23 / tau)
__global__ void diag_kernel(const __bf16* __restrict__ p1,
                            const __bf16* __restrict__ p2,
                            const __bf16* __restrict__ p3,
                            float* __restrict__ dg)
{
  const int row = blockIdx.x * 4 + (threadIdx.x >> 6);
  const int l = threadIdx.x & 63;
  if (row >= N_ROWS) return;
  const size_t base = (size_t)row * D + l * 4;
  const bf16x4 a = *(const bf16x4*)(p1 + base);
  const bf16x4 b = *(const bf16x4*)(p2 + base);
  const bf16x4 e = *(const bf16x4*)(p3 + base);
  float d11 = 0, d22 = 0, d12 = 0, d13 = 0, d23 = 0;
#pragma unroll
  for (int q = 0; q < 4; ++q) {
    const float fa = (float)a[q], fb = (float)b[q], fe = (float)e[q];
    d11 += fa * fa; d22 += fb * fb; d12 += fa * fb;
    d13 += fa * fe; d23 += fb * fe;
  }
#pragma unroll
  for (int mask = 1; mask < 64; mask <<= 1) {
    d11 += __shfl_xor(d11, mask, 64);
    d22 += __shfl_xor(d22, mask, 64);
    d12 += __shfl_xor(d12, mask, 64);
    d13 += __shfl_xor(d13, mask, 64);
    d23 += __shfl_xor(d23, mask, 64);
  }
  if (l == 0) {
    dg[0 * NP + row] = __expf(d11 * INV_TAU);
    dg[1 * NP + row] = __expf(d22 * INV_TAU);
    dg[2 * NP + row] = __expf(d12 * INV_TAU);
    dg[3 * NP + row] = __expf(d13 * INV_TAU);
    dg[4 * NP + row] = __expf(d23 * INV_TAU);
  }
}

__global__ void loss_kernel(const float* __restrict__ S,
                            const float* __restrict__ dg,
                            float* __restrict__ out)
{
  float local = 0.f;
  for (int i = blockIdx.x * blockDim.x + threadIdx.x; i < N_ROWS;
       i += gridDim.x * blockDim.x) {
    const float s11 = S[0 * NP + i] - PADF;
    const float s12 = S[1 * NP + i] - PADF;
    const float s13 = S[2 * NP + i] - PADF;
    const float s21 = S[3 * NP + i] - PADF;
    const float s22 = S[4 * NP + i] - PADF;
    const float s23 = S[5 * NP + i] - PADF;
    const float d11 = dg[0 * NP + i], d22 = dg[1 * NP + i];
    const float d12 = dg[2 * NP + i], d13 = dg[3 * NP + i];
    const float d23 = dg[4 * NP + i];
    const float den1 = s11 + s12 + s13 - d11 - d12 - d13;
    const float den2 = s22 + s21 + s23 - d22 - d12 - d23;
    local += 0.5f * (__logf(den1) + __logf(den2)) - __logf(d12);
  }
#pragma unroll
  for (int mask = 1; mask < 64; mask <<= 1) local += __shfl_xor(local, mask, 64);
  __shared__ float wsum[4];
  if ((threadIdx.x & 63) == 0) wsum[threadIdx.x >> 6] = local;
  __syncthreads();
  if (threadIdx.x == 0) {
    const float t = wsum[0] + wsum[1] + wsum[2] + wsum[3];
    atomicAdd(out, t * (1.0f / (float)N_ROWS));
  }
}

// ---------------------------------------------------------------------------
extern "C" void kernel_launch(void* const* d_in, const int* in_sizes, int n_in,
                              void* d_out, int out_size, void* d_ws,
                              size_t ws_size, hipStream_t stream)
{
  const float* z[3] = {(const float*)d_in[0], (const float*)d_in[1],
                       (const float*)d_in[2]};
  const float* W1 = (const float*)d_in[3];
  const float* b1 = (const float*)d_in[4];
  const float* W2 = (const float*)d_in[5];
  const float* b2 = (const float*)d_in[6];

  char* ws = (char*)d_ws;
  size_t off = 0;
  auto alloc = [&](size_t bytes) -> char* {
    char* p = ws + off;
    off += (bytes + 511) & ~(size_t)511;
    return p;
  };
  __bf16* pB[3];
  for (int m = 0; m < 3; ++m) pB[m] = (__bf16*)alloc((size_t)NP * D * 2);
  __bf16* w1b  = (__bf16*)alloc((size_t)D * D * 2);
  __bf16* w2b  = (__bf16*)alloc((size_t)D * D * 2);
  __bf16* zb   = (__bf16*)alloc((size_t)NP * D * 2);
  __bf16* hB   = (__bf16*)alloc((size_t)NP * D * 2);
  float*  praw = (float*) alloc((size_t)NP * D * 4);
  float*  Sv   = (float*) alloc((size_t)6 * NP * 4);
  float*  dg   = (float*) alloc((size_t)5 * NP * 4);

  hipMemsetAsync(Sv, 0, (size_t)6 * NP * 4, stream);
  hipMemsetAsync(d_out, 0, sizeof(float), stream);

  cast_kernel<<<64, 256, 0, stream>>>(W1, w1b, D * D);
  cast_kernel<<<64, 256, 0, stream>>>(W2, w2b, D * D);

  for (int m = 0; m < 3; ++m) {
    cast_kernel<<<2500, 256, 0, stream>>>(z[m], zb, N_ROWS * D);
    dim3 g(PT, 2);
    proj_kernel<0><<<g, 256, 0, stream>>>(zb, w1b, b1, (void*)hB);
    proj_kernel<1><<<g, 256, 0, stream>>>(hB, w2b, b2, (void*)praw);
    norm_kernel<<<NP / 4, 256, 0, stream>>>(praw, pB[m]);
  }

  gram_kernel<<<NWGG, 256, 0, stream>>>(pB[0], pB[1], pB[2], Sv);
  diag_kernel<<<2500, 256, 0, stream>>>(pB[0], pB[1], pB[2], dg);
  loss_kernel<<<64, 256, 0, stream>>>(Sv, dg, (float*)d_out);
}

// Round 9
// 316.354 us; speedup vs baseline: 1.2345x; 1.2345x over previous
//
#include <hip/hip_runtime.h>
#include <hip/hip_bf16.h>
#include <math.h>

#define AS1 __attribute__((address_space(1)))
#define AS3 __attribute__((address_space(3)))

typedef __bf16 bf16x8 __attribute__((ext_vector_type(8)));
typedef __bf16 bf16x4 __attribute__((ext_vector_type(4)));
typedef float  f32x4  __attribute__((ext_vector_type(4)));

static constexpr int   N_ROWS   = 10000;
static constexpr int   D        = 256;           // K for all GEMMs
static constexpr float INV_TAU  = 2.0f;          // 1/0.5

// gram tiling: 128x128 tiles, rows padded to 10112
static constexpr int   T        = 79;            // ceil(10000/128)
static constexpr int   NP       = T * 128;       // 10112
static constexpr float PADF     = 112.0f;        // NP - N_ROWS (exp(0)=1 each)
static constexpr int   SPR     = 10;             // strips per row (ceil(79/8))
static constexpr int   BPJ     = T * SPR;        // 790 strip-blocks per job
static constexpr int   NWGG    = 5 * BPJ;        // 3950

// proj tiling (128x128 structure)
static constexpr int   PT       = 79;

// ---------------------------------------------------------------------------
// 128x128 tile GEMM helper (projection GEMMs only). K=256, BK=64,
// single-buffer, XOR-swizzled LDS via pre-swizzled global_load_lds source.
// ---------------------------------------------------------------------------
__device__ __forceinline__ void tile_gemm_128(
    const __bf16* __restrict__ Abase, const __bf16* __restrict__ Bbase,
    char* ldsA, char* ldsB, int tid, f32x4 acc[4][4])
{
  const int l      = tid & 63;
  const int wr     = (tid >> 7) & 1;
  const int wc     = (tid >> 6) & 1;
  const int srow   = tid >> 3;
  const int schunk = tid & 7;
  const int lrow   = l & 15;
  const int lk     = l >> 4;

  for (int kt = 0; kt < 4; ++kt) {
    __syncthreads();
    const int kbase = kt * 64;
#pragma unroll
    for (int rr = 0; rr < 4; ++rr) {
      const int row = rr * 32 + srow;
      const int lc  = schunk ^ (row & 7);
      const __bf16* ga = Abase + (size_t)row * D + kbase + lc * 8;
      const __bf16* gb = Bbase + (size_t)row * D + kbase + lc * 8;
      __builtin_amdgcn_global_load_lds((const AS1 void*)ga,
          (AS3 void*)(ldsA + rr * 4096 + tid * 16), 16, 0, 0);
      __builtin_amdgcn_global_load_lds((const AS1 void*)gb,
          (AS3 void*)(ldsB + rr * 4096 + tid * 16), 16, 0, 0);
    }
    __syncthreads();
#pragma unroll
    for (int ks = 0; ks < 2; ++ks) {
      bf16x8 af[4], bfr[4];
#pragma unroll
      for (int m = 0; m < 4; ++m) {
        const int row = wr * 64 + m * 16 + lrow;
        const int off = row * 128 + ((ks * 64 + lk * 16) ^ ((row & 7) << 4));
        af[m] = *(const bf16x8*)(ldsA + off);
      }
#pragma unroll
      for (int n = 0; n < 4; ++n) {
        const int row = wc * 64 + n * 16 + lrow;
        const int off = row * 128 + ((ks * 64 + lk * 16) ^ ((row & 7) << 4));
        bfr[n] = *(const bf16x8*)(ldsB + off);
      }
#pragma unroll
      for (int m = 0; m < 4; ++m)
#pragma unroll
        for (int n = 0; n < 4; ++n)
          acc[m][n] = __builtin_amdgcn_mfma_f32_16x16x32_bf16(
              af[m], bfr[n], acc[m][n], 0, 0, 0);
    }
  }
}

// ---------------------------------------------------------------------------
// Gram kernel, strip-mined, A-panel PERSISTENT IN LDS: each block owns up to
// 8 tiles (128x128) sharing one A-panel row r. A (128x256 bf16 = 64 KiB) is
// staged into LDS ONCE per strip; B is double-buffered at BK=32 (2x8 KiB).
// Total LDS 80 KiB -> 2 blocks/CU truly co-resident (VGPR ~90), which covers
// barrier/prologue/epilogue stalls. Per-step global traffic: 8 KB (B only),
// 45% less total cache traffic than r7; LDS writes halved. Plain
// __syncthreads depth-1 pipeline (stage B(i+1) right after the barrier).
// A layout: [128 rows][32 chunks of 16B], swizzle chunk^(row&15) -> 2-way
// banks (free); staged via inverse-swizzled global source.
// ---------------------------------------------------------------------------
__global__ __launch_bounds__(256, 2) void gram_kernel(
    const __bf16* __restrict__ p1, const __bf16* __restrict__ p2,
    const __bf16* __restrict__ p3, float* __restrict__ S)
{
  const int bid = blockIdx.x;
  const int job = bid / BPJ;
  const int t0  = bid % BPJ;
  const int r   = t0 / SPR;
  const int s   = t0 % SPR;
  int cstart = s * 8;
  const int cend = min(cstart + 8, T);

  const __bf16 *P, *Q;
  float *Srow, *Scol;
  bool sym = false;
  if (job == 0)      { P = p1; Q = p2; Srow = S + 1 * NP; Scol = S + 3 * NP; }
  else if (job == 1) { P = p1; Q = p3; Srow = S + 2 * NP; Scol = nullptr; }
  else if (job == 2) { P = p2; Q = p3; Srow = S + 5 * NP; Scol = nullptr; }
  else if (job == 3) { P = p1; Q = p1; Srow = S + 0 * NP; Scol = S + 0 * NP;
                       sym = true; cstart = max(cstart, r); }
  else               { P = p2; Q = p2; Srow = S + 4 * NP; Scol = S + 4 * NP;
                       sym = true; cstart = max(cstart, r); }
  const int len = cend - cstart;
  if (len <= 0) return;
  const int nsteps = len * 8;

  // A panel 64 KiB persistent | B 2 x 8 KiB double buffer  = 80 KiB
  __shared__ __align__(16) char lds[81920];
  char* ldsB = lds + 65536;

  const int tid  = threadIdx.x;
  const int l    = tid & 63;
  const int wave = tid >> 6;
  const int wr   = wave >> 1;      // 64-row half
  const int wc   = wave & 1;       // 64-col half
  const int lrow = l & 15;
  const int lk   = l >> 4;

  // A read offsets: frag m, step kt -> byte off =
  //   row*512 + (((kt*4+lk) ^ (row&15)) << 4)
  int abase[4], arx[4];
#pragma unroll
  for (int m = 0; m < 4; ++m) {
    const int row = wr * 64 + m * 16 + lrow;
    abase[m] = row * 512;
    arx[m]   = row & 15;
  }

  // B-frag LDS read offsets in an 8 KiB [128 rows][4 chunks] slab
  int offB[4];
#pragma unroll
  for (int n = 0; n < 4; ++n) {
    const int row = wc * 64 + n * 16 + lrow;
    offB[n] = row * 64 + ((lk ^ ((row >> 1) & 3)) << 4);
  }

  // B staging: 512 16B-chunks per slab, 2 per thread, inverse-swizzled src
  const int pos0 = tid, pos1 = tid + 256;
  const int row0 = pos0 >> 2, lc0 = (pos0 & 3) ^ ((row0 >> 1) & 3);
  const int row1 = pos1 >> 2, lc1 = (pos1 & 3) ^ ((row1 >> 1) & 3);
  const int boff0 = row0 * D + lc0 * 8;
  const int boff1 = row1 * D + lc1 * 8;

  auto stageB = [&](int buf, int i) {
    const int c  = cstart + (i >> 3);
    const int kb = (i & 7) * 32;
    const __bf16* B0 = Q + (size_t)c * 128 * D + kb;
    char* lb = ldsB + buf * 8192;
    __builtin_amdgcn_global_load_lds((const AS1 void*)(B0 + boff0),
        (AS3 void*)(lb + pos0 * 16), 16, 0, 0);
    __builtin_amdgcn_global_load_lds((const AS1 void*)(B0 + boff1),
        (AS3 void*)(lb + pos1 * 16), 16, 0, 0);
  };

  // ---- stage A panel once per strip (16 chunks per thread) ----
  const __bf16* Abase = P + (size_t)r * 128 * D;
#pragma unroll
  for (int j = 0; j < 16; ++j) {
    const int p = tid + j * 256;          // 0..4095 (row*32 + chunk)
    const int row = p >> 5, pc = p & 31;
    __builtin_amdgcn_global_load_lds(
        (const AS1 void*)(Abase + (size_t)row * D + (pc ^ (row & 15)) * 8),
        (AS3 void*)(lds + p * 16), 16, 0, 0);
  }
  stageB(0, 0);

  f32x4 rsum[4];
#pragma unroll
  for (int m = 0; m < 4; ++m)
#pragma unroll
    for (int q = 0; q < 4; ++q) rsum[m][q] = 0.f;

  for (int tt = 0; tt < len; ++tt) {
    f32x4 acc[4][4];
#pragma unroll
    for (int m = 0; m < 4; ++m)
#pragma unroll
      for (int n = 0; n < 4; ++n)
#pragma unroll
        for (int q = 0; q < 4; ++q) acc[m][n][q] = 0.f;

#pragma unroll
    for (int kt = 0; kt < 8; ++kt) {
      const int i = tt * 8 + kt;
      __syncthreads();                     // slab i (and A) staged & visible
      if (i + 1 < nsteps) stageB((i + 1) & 1, i + 1);
      const char* lb = ldsB + (i & 1) * 8192;
      bf16x8 af[4], bfr[4];
      const int ach = kt * 4 + lk;
#pragma unroll
      for (int m = 0; m < 4; ++m)
        af[m] = *(const bf16x8*)(lds + abase[m] + ((ach ^ arx[m]) << 4));
#pragma unroll
      for (int n = 0; n < 4; ++n) bfr[n] = *(const bf16x8*)(lb + offB[n]);
#pragma unroll
      for (int m = 0; m < 4; ++m)
#pragma unroll
        for (int n = 0; n < 4; ++n)
          acc[m][n] = __builtin_amdgcn_mfma_f32_16x16x32_bf16(
              af[m], bfr[n], acc[m][n], 0, 0, 0);
    }

    // ---- tile epilogue (runs while next B slab's loads are in flight) ----
    const int c = cstart + tt;
#pragma unroll
    for (int m = 0; m < 4; ++m)
#pragma unroll
      for (int n = 0; n < 4; ++n)
#pragma unroll
        for (int q = 0; q < 4; ++q)
          acc[m][n][q] = __expf(acc[m][n][q] * INV_TAU);

#pragma unroll
    for (int m = 0; m < 4; ++m)
      rsum[m] += acc[m][0] + acc[m][1] + acc[m][2] + acc[m][3];

    const bool docol = Scol && (!sym || c > r);
    if (docol) {
#pragma unroll
      for (int n = 0; n < 4; ++n) {
        float sc = 0.f;
#pragma unroll
        for (int m = 0; m < 4; ++m)
#pragma unroll
          for (int q = 0; q < 4; ++q) sc += acc[m][n][q];
        sc += __shfl_xor(sc, 16, 64);
        sc += __shfl_xor(sc, 32, 64);
        if (l < 16) atomicAdd(&Scol[c * 128 + wc * 64 + n * 16 + l], sc);
      }
    }
  }

  // ---- strip epilogue: row sums (one atomic set per strip) ----
#pragma unroll
  for (int m = 0; m < 4; ++m) {
#pragma unroll
    for (int mask = 1; mask < 16; mask <<= 1)
#pragma unroll
      for (int q = 0; q < 4; ++q)
        rsum[m][q] += __shfl_xor(rsum[m][q], mask, 64);
    if ((l & 15) == 0) {
      const int grow = r * 128 + wr * 64 + m * 16 + lk * 4;
#pragma unroll
      for (int q = 0; q < 4; ++q) atomicAdd(&Srow[grow + q], rsum[m][q]);
    }
  }
}

// ---------------------------------------------------------------------------
// Projection GEMM: C = A @ B^T + bias, MODE 0: elu -> bf16, MODE 1: f32.
// ---------------------------------------------------------------------------
template <int MODE>
__global__ __launch_bounds__(256, 2) void proj_kernel(
    const __bf16* __restrict__ A, const __bf16* __restrict__ B,
    const float* __restrict__ bias, void* __restrict__ out)
{
  const int r = blockIdx.x, c = blockIdx.y;
  __shared__ __align__(16) char lds[32768];
  f32x4 acc[4][4];
#pragma unroll
  for (int m = 0; m < 4; ++m)
#pragma unroll
    for (int n = 0; n < 4; ++n)
#pragma unroll
      for (int q = 0; q < 4; ++q) acc[m][n][q] = 0.f;

  tile_gemm_128(A + (size_t)r * 128 * D, B + (size_t)c * 128 * D,
                lds, lds + 16384, threadIdx.x, acc);

  const int tid = threadIdx.x, l = tid & 63;
  const int wr = (tid >> 7) & 1, wc = (tid >> 6) & 1;
#pragma unroll
  for (int n = 0; n < 4; ++n) {
    const int gcol = c * 128 + wc * 64 + n * 16 + (l & 15);
    const float bn = bias[gcol];
#pragma unroll
    for (int m = 0; m < 4; ++m) {
#pragma unroll
      for (int q = 0; q < 4; ++q) {
        const int grow = r * 128 + wr * 64 + m * 16 + (l >> 4) * 4 + q;
        float v = acc[m][n][q] + bn;
        if (MODE == 0) {
          float o = v > 0.f ? v : (__expf(v) - 1.f);   // ELU
          ((__bf16*)out)[(size_t)grow * D + gcol] = (__bf16)o;
        } else {
          ((float*)out)[(size_t)grow * D + gcol] = v;
        }
      }
    }
  }
}

// ---------------------------------------------------------------------------
__global__ void cast_kernel(const float* __restrict__ src,
                            __bf16* __restrict__ dst, int n)
{
  int idx = (blockIdx.x * blockDim.x + threadIdx.x) * 4;
  const int stride = gridDim.x * blockDim.x * 4;
  for (; idx < n; idx += stride) {
    const float4 v = *(const float4*)(src + idx);
    bf16x4 o;
    o[0] = (__bf16)v.x; o[1] = (__bf16)v.y;
    o[2] = (__bf16)v.z; o[3] = (__bf16)v.w;
    *(bf16x4*)(dst + idx) = o;
  }
}

// one wave per row: L2-normalize; padded rows written as exact zeros
__global__ void norm_kernel(const float* __restrict__ praw,
                            __bf16* __restrict__ p)
{
  const int row = blockIdx.x * 4 + (threadIdx.x >> 6);
  const int l = threadIdx.x & 63;
  const size_t base = (size_t)row * D + l * 4;
  if (row < N_ROWS) {
    const float4 v = *(const float4*)(praw + base);
    float ss = v.x * v.x + v.y * v.y + v.z * v.z + v.w * v.w;
#pragma unroll
    for (int mask = 1; mask < 64; mask <<= 1) ss += __shfl_xor(ss, mask, 64);
    const float inv = 1.0f / fmaxf(sqrtf(ss), 1e-12f);
    bf16x4 o;
    o[0] = (__bf16)(v.x * inv); o[1] = (__bf16)(v.y * inv);
    o[2] = (__bf16)(v.z * inv); o[3] = (__bf16)(v.w * inv);
    *(bf16x4*)(p + base) = o;
  } else {
    bf16x4 o;
    o[0] = o[1] = o[2] = o[3] = (__bf16)0.0f;
    *(bf16x4*)(p + base) = o;
  }
}

// per-row diagonal terms: dg [5][NP] = exp(d11,d22,d12,d13,d23 / tau)
__global__ void diag_kernel(const __bf16* __restrict__ p1,
                            const __bf16* __restrict__ p2,
                            const __bf16* __restrict__ p3,
                            float* __restrict__ dg)
{
  const int row = blockIdx.x * 4 + (threadIdx.x >> 6);
  const int l = threadIdx.x & 63;
  if (row >= N_ROWS) return;
  const size_t base = (size_t)row * D + l * 4;
  const bf16x4 a = *(const bf16x4*)(p1 + base);
  const bf16x4 b = *(const bf16x4*)(p2 + base);
  const bf16x4 e = *(const bf16x4*)(p3 + base);
  float d11 = 0, d22 = 0, d12 = 0, d13 = 0, d23 = 0;
#pragma unroll
  for (int q = 0; q < 4; ++q) {
    const float fa = (float)a[q], fb = (float)b[q], fe = (float)e[q];
    d11 += fa * fa; d22 += fb * fb; d12 += fa * fb;
    d13 += fa * fe; d23 += fb * fe;
  }
#pragma unroll
  for (int mask = 1; mask < 64; mask <<= 1) {
    d11 += __shfl_xor(d11, mask, 64);
    d22 += __shfl_xor(d22, mask, 64);
    d12 += __shfl_xor(d12, mask, 64);
    d13 += __shfl_xor(d13, mask, 64);
    d23 += __shfl_xor(d23, mask, 64);
  }
  if (l == 0) {
    dg[0 * NP + row] = __expf(d11 * INV_TAU);
    dg[1 * NP + row] = __expf(d22 * INV_TAU);
    dg[2 * NP + row] = __expf(d12 * INV_TAU);
    dg[3 * NP + row] = __expf(d13 * INV_TAU);
    dg[4 * NP + row] = __expf(d23 * INV_TAU);
  }
}

__global__ void loss_kernel(const float* __restrict__ S,
                            const float* __restrict__ dg,
                            float* __restrict__ out)
{
  float local = 0.f;
  for (int i = blockIdx.x * blockDim.x + threadIdx.x; i < N_ROWS;
       i += gridDim.x * blockDim.x) {
    const float s11 = S[0 * NP + i] - PADF;
    const float s12 = S[1 * NP + i] - PADF;
    const float s13 = S[2 * NP + i] - PADF;
    const float s21 = S[3 * NP + i] - PADF;
    const float s22 = S[4 * NP + i] - PADF;
    const float s23 = S[5 * NP + i] - PADF;
    const float d11 = dg[0 * NP + i], d22 = dg[1 * NP + i];
    const float d12 = dg[2 * NP + i], d13 = dg[3 * NP + i];
    const float d23 = dg[4 * NP + i];
    const float den1 = s11 + s12 + s13 - d11 - d12 - d13;
    const float den2 = s22 + s21 + s23 - d22 - d12 - d23;
    local += 0.5f * (__logf(den1) + __logf(den2)) - __logf(d12);
  }
#pragma unroll
  for (int mask = 1; mask < 64; mask <<= 1) local += __shfl_xor(local, mask, 64);
  __shared__ float wsum[4];
  if ((threadIdx.x & 63) == 0) wsum[threadIdx.x >> 6] = local;
  __syncthreads();
  if (threadIdx.x == 0) {
    const float t = wsum[0] + wsum[1] + wsum[2] + wsum[3];
    atomicAdd(out, t * (1.0f / (float)N_ROWS));
  }
}

// ---------------------------------------------------------------------------
extern "C" void kernel_launch(void* const* d_in, const int* in_sizes, int n_in,
                              void* d_out, int out_size, void* d_ws,
                              size_t ws_size, hipStream_t stream)
{
  const float* z[3] = {(const float*)d_in[0], (const float*)d_in[1],
                       (const float*)d_in[2]};
  const float* W1 = (const float*)d_in[3];
  const float* b1 = (const float*)d_in[4];
  const float* W2 = (const float*)d_in[5];
  const float* b2 = (const float*)d_in[6];

  char* ws = (char*)d_ws;
  size_t off = 0;
  auto alloc = [&](size_t bytes) -> char* {
    char* p = ws + off;
    off += (bytes + 511) & ~(size_t)511;
    return p;
  };
  __bf16* pB[3];
  for (int m = 0; m < 3; ++m) pB[m] = (__bf16*)alloc((size_t)NP * D * 2);
  __bf16* w1b  = (__bf16*)alloc((size_t)D * D * 2);
  __bf16* w2b  = (__bf16*)alloc((size_t)D * D * 2);
  __bf16* zb   = (__bf16*)alloc((size_t)NP * D * 2);
  __bf16* hB   = (__bf16*)alloc((size_t)NP * D * 2);
  float*  praw = (float*) alloc((size_t)NP * D * 4);
  float*  Sv   = (float*) alloc((size_t)6 * NP * 4);
  float*  dg   = (float*) alloc((size_t)5 * NP * 4);

  hipMemsetAsync(Sv, 0, (size_t)6 * NP * 4, stream);
  hipMemsetAsync(d_out, 0, sizeof(float), stream);

  cast_kernel<<<64, 256, 0, stream>>>(W1, w1b, D * D);
  cast_kernel<<<64, 256, 0, stream>>>(W2, w2b, D * D);

  for (int m = 0; m < 3; ++m) {
    cast_kernel<<<2500, 256, 0, stream>>>(z[m], zb, N_ROWS * D);
    dim3 g(PT, 2);
    proj_kernel<0><<<g, 256, 0, stream>>>(zb, w1b, b1, (void*)hB);
    proj_kernel<1><<<g, 256, 0, stream>>>(hB, w2b, b2, (void*)praw);
    norm_kernel<<<NP / 4, 256, 0, stream>>>(praw, pB[m]);
  }

  gram_kernel<<<NWGG, 256, 0, stream>>>(pB[0], pB[1], pB[2], Sv);
  diag_kernel<<<2500, 256, 0, stream>>>(pB[0], pB[1], pB[2], dg);
  loss_kernel<<<64, 256, 0, stream>>>(Sv, dg, (float*)d_out);
}